// Round 9
// baseline (268.899 us; speedup 1.0000x reference)
//
#include <hip/hip_runtime.h>
#include <hip/hip_bf16.h>
#include <math.h>

#define B_ 2
#define S_ 2048
#define D_ 1024
#define H_ 16
#define RANK_ 128
#define NC_ 16
#define DH_ 64
#define T_ (B_*S_)
#define NZ_ 2176          // z cols: 2048 z | 64 scores | 64 pad

typedef __attribute__((ext_vector_type(8))) __bf16 bf16x8;
typedef __attribute__((ext_vector_type(8))) unsigned short u16x8;
typedef __attribute__((ext_vector_type(4))) float f32x4;

#if __has_builtin(__builtin_amdgcn_exp2f)
#define EXP2F(x) __builtin_amdgcn_exp2f(x)
#else
#define EXP2F(x) exp2f(x)
#endif

__device__ __forceinline__ unsigned short f2bu(float f) {
    __hip_bfloat16 h = __float2bfloat16(f);
    unsigned short u; __builtin_memcpy(&u, &h, 2); return u;
}
__device__ __forceinline__ float bu2f(unsigned short u) {
    __hip_bfloat16 h; __builtin_memcpy(&h, &u, 2); return __bfloat162float(h);
}

// async global->LDS 16B/lane; LDS dst = wave-uniform base (+ lane*16 implied)
__device__ __forceinline__ void gl_lds16(const unsigned short* g, unsigned short* l) {
    __builtin_amdgcn_global_load_lds(
        (const __attribute__((address_space(1))) void*)g,
        (__attribute__((address_space(3))) void*)l, 16, 0, 0);
}

__device__ __forceinline__ bool sniff_f32(const unsigned* __restrict__ p) {
    int votes = 0;
    #pragma unroll
    for (int i = 0; i < 64; i++) {
        unsigned e = (p[i] >> 23) & 0xFFu;
        votes += (e >= 0x60u && e <= 0x8Fu) ? 1 : 0;
    }
    return votes >= 32;
}

// ---------------------------------------------------------------------------
// merged input stage: blocks 0..511 = convert+transpose C; rest = flat converts
// ---------------------------------------------------------------------------
struct Cvt { const void* src[9]; unsigned short* dst[9]; const void* C; unsigned short* Ct; };

__global__ __launch_bounds__(256) void k_inputs(Cvt cv,
    const unsigned* __restrict__ probe)
{
    bool f32 = sniff_f32(probe);
    if (blockIdx.x < 512) {
        int bid = blockIdx.x;
        int d0 = (bid & 15) * 64, r0 = ((bid >> 4) & 1) * 64, n = bid >> 5;
        __shared__ unsigned short tile[64][65];
        for (int idx = threadIdx.x; idx < 4096; idx += 256) {
            int row = idx >> 6, col = idx & 63;
            size_t si = ((size_t)n*D_ + d0 + row)*RANK_ + r0 + col;
            tile[row][col] = f32 ? f2bu(((const float*)cv.C)[si])
                                 : ((const unsigned short*)cv.C)[si];
        }
        __syncthreads();
        for (int idx = threadIdx.x; idx < 4096; idx += 256) {
            int row = idx >> 6, col = idx & 63;
            cv.Ct[((size_t)(n*RANK_ + r0 + row))*D_ + d0 + col] = tile[col][row];
        }
        return;
    }
    const int offs[9] = {0, 4194304, 4210688, 4227072, 4243456,
                         4259840, 4390912, 4521984, 4653056};
    const int total = 5701632;
    int nconv = gridDim.x - 512;
    int stride = nconv * 256;
    for (int i = (blockIdx.x - 512) * 256 + threadIdx.x; i < total; i += stride) {
        int seg = 0;
        #pragma unroll
        for (int s = 1; s < 9; s++) seg += (i >= offs[s]) ? 1 : 0;
        int local = i - offs[seg];
        const void* sp = cv.src[seg];
        unsigned short v = 0;
        if (sp) v = f32 ? f2bu(((const float*)sp)[local]) : ((const unsigned short*)sp)[local];
        cv.dst[seg][local] = v;
    }
}

// ---------------------------------------------------------------------------
// MFMA NT GEMM, async-staged. Tile (MT*32)x128, BK=32.
// MODE: 0 = bf16 out; 2 = runtime-sniffed out dtype (fp32 vs bf16)
// ---------------------------------------------------------------------------
template<int MT, int MODE>
__global__ __launch_bounds__(256) void k_mfma_gemm(const unsigned short* __restrict__ A,
    const unsigned short* __restrict__ Bm, void* __restrict__ Cout,
    const unsigned* __restrict__ probe, int M, int N, int K)
{
    bool f32out = false;
    if (MODE == 2) f32out = sniff_f32(probe);
    __shared__ __align__(16) unsigned short As[MT*32*32];
    __shared__ __align__(16) unsigned short Bs[128*32];
    const int tid = threadIdx.x;
    const int wv = tid >> 6, lane = tid & 63;
    const int wm = (wv >> 1) * (MT*16), wn = (wv & 1) * 64;
    const int quad = lane >> 4, l16 = lane & 15;
    const int m0 = blockIdx.x * (MT*32), n0 = blockIdx.y * 128;

    const f32x4 z4 = {0.f, 0.f, 0.f, 0.f};
    f32x4 acc[MT][4];
    #pragma unroll
    for (int i = 0; i < MT; i++)
        #pragma unroll
        for (int j = 0; j < 4; j++) acc[i][j] = z4;

    for (int k0 = 0; k0 < K; k0 += 32) {
        __syncthreads();
        #pragma unroll
        for (int c = 0; c < MT/2; c++) {
            int idx = wv*64 + c*256 + lane;
            gl_lds16(A + (size_t)(m0 + (idx >> 2))*K + k0 + (idx & 3)*8,
                     &As[(wv*64 + c*256)*8]);
        }
        #pragma unroll
        for (int c = 0; c < 2; c++) {
            int idx = wv*64 + c*256 + lane;
            gl_lds16(Bm + (size_t)(n0 + (idx >> 2))*K + k0 + (idx & 3)*8,
                     &Bs[(wv*64 + c*256)*8]);
        }
        __syncthreads();
        bf16x8 af[MT], bfr[4];
        #pragma unroll
        for (int mt = 0; mt < MT; mt++) af[mt]  = *(const bf16x8*)&As[(wm + mt*16 + l16)*32 + quad*8];
        #pragma unroll
        for (int nt = 0; nt < 4; nt++) bfr[nt] = *(const bf16x8*)&Bs[(wn + nt*16 + l16)*32 + quad*8];
        #pragma unroll
        for (int mt = 0; mt < MT; mt++)
            #pragma unroll
            for (int nt = 0; nt < 4; nt++)
                acc[mt][nt] = __builtin_amdgcn_mfma_f32_16x16x32_bf16(af[mt], bfr[nt], acc[mt][nt], 0, 0, 0);
    }
    #pragma unroll
    for (int mt = 0; mt < MT; mt++)
        #pragma unroll
        for (int nt = 0; nt < 4; nt++) {
            int col = n0 + wn + nt*16 + l16;
            #pragma unroll
            for (int r = 0; r < 4; r++) {
                int rowg = m0 + wm + mt*16 + quad*4 + r;
                float v = acc[mt][nt][r];
                if (MODE == 2 && f32out) ((float*)Cout)[(size_t)rowg*N + col] = v;
                else  ((unsigned short*)Cout)[(size_t)rowg*N + col] = f2bu(v);
            }
        }
}

// ---------------------------------------------------------------------------
// merged Q|K + V^T GEMMs (K=128), one launch, 768 blocks.
// blocks 0..511:  D[tok][Q|K col] = h_w[tok][:] . wqkv_w[col][:]  (Q scaled)
// blocks 512..767: D[dv][tok] = wV[dv][:] . h_v[tok][:] -> Vtg[(b*H+h)*64+dh][s]
// ---------------------------------------------------------------------------
__global__ __launch_bounds__(256) void k_qkv2(const unsigned short* __restrict__ h3,
    const unsigned short* __restrict__ wqkv, unsigned short* __restrict__ QKb,
    unsigned short* __restrict__ Vtg)
{
    __shared__ __align__(16) unsigned short As[128*32];
    __shared__ __align__(16) unsigned short Bs[128*32];
    const int tid = threadIdx.x;
    const int wv = tid >> 6, lane = tid & 63;
    const int wm = (wv >> 1) * 64, wn = (wv & 1) * 64;
    const int quad = lane >> 4, l16 = lane & 15;

    const bool vt = (blockIdx.x >= 512);
    int m0, n0;
    const unsigned short *A, *Bm;
    float scale = 1.f;
    if (!vt) {
        int id = blockIdx.x;
        m0 = (id & 31) * 128;                 // tokens
        n0 = (id >> 5) * 128;                 // Q|K cols (0..2047)
        int w = n0 >> 10;
        A  = h3 + (size_t)w * T_ * RANK_ + (size_t)m0 * RANK_;   // FIX: + m0 rows
        Bm = wqkv + (size_t)w * D_ * RANK_ + (size_t)(n0 & 1023) * RANK_;
        if (w == 0) scale = 0.125f * 1.44269504f;
    } else {
        int id = blockIdx.x - 512;
        m0 = (id & 7) * 128;                  // dv rows
        n0 = (id >> 3) * 128;                 // tokens
        A  = wqkv + (size_t)2 * D_ * RANK_ + (size_t)m0 * RANK_;
        Bm = h3 + (size_t)2 * T_ * RANK_ + (size_t)n0 * RANK_;
    }

    const f32x4 z4 = {0.f, 0.f, 0.f, 0.f};
    f32x4 acc[4][4];
    #pragma unroll
    for (int i = 0; i < 4; i++)
        #pragma unroll
        for (int j = 0; j < 4; j++) acc[i][j] = z4;

    for (int k0 = 0; k0 < RANK_; k0 += 32) {
        __syncthreads();
        #pragma unroll
        for (int c = 0; c < 2; c++) {
            int idx = wv*64 + c*256 + lane;
            gl_lds16(A  + (size_t)(idx >> 2)*RANK_ + k0 + (idx & 3)*8,
                     &As[(wv*64 + c*256)*8]);
            gl_lds16(Bm + (size_t)(idx >> 2)*RANK_ + k0 + (idx & 3)*8,
                     &Bs[(wv*64 + c*256)*8]);
        }
        __syncthreads();
        bf16x8 af[4], bfr[4];
        #pragma unroll
        for (int mt = 0; mt < 4; mt++) af[mt]  = *(const bf16x8*)&As[(wm + mt*16 + l16)*32 + quad*8];
        #pragma unroll
        for (int nt = 0; nt < 4; nt++) bfr[nt] = *(const bf16x8*)&Bs[(wn + nt*16 + l16)*32 + quad*8];
        #pragma unroll
        for (int mt = 0; mt < 4; mt++)
            #pragma unroll
            for (int nt = 0; nt < 4; nt++)
                acc[mt][nt] = __builtin_amdgcn_mfma_f32_16x16x32_bf16(af[mt], bfr[nt], acc[mt][nt], 0, 0, 0);
    }
    #pragma unroll
    for (int mt = 0; mt < 4; mt++)
        #pragma unroll
        for (int nt = 0; nt < 4; nt++) {
            #pragma unroll
            for (int r = 0; r < 4; r++) {
                int rowg = m0 + wm + mt*16 + quad*4 + r;
                int col  = n0 + wn + nt*16 + l16;
                float v = acc[mt][nt][r] * scale;
                if (!vt) {
                    QKb[(size_t)(col >> 10)*T_*D_ + (size_t)rowg*D_ + (col & 1023)]
                        = f2bu(v);
                } else {
                    size_t vrow = (size_t)((col >> 11)*H_ + (rowg >> 6))*64 + (rowg & 63);
                    Vtg[vrow*S_ + (col & 2047)] = f2bu(v);
                }
            }
        }
}

// ---------------------------------------------------------------------------
// hreduce + router softmax (scores in z cols 2048..2095)
// ---------------------------------------------------------------------------
__global__ __launch_bounds__(256) void k_hreduce(const unsigned short* __restrict__ z,
    unsigned short* __restrict__ h)
{
    int t0 = blockIdx.x * 2;
    int tg = threadIdx.x >> 7, r = threadIdx.x & 127;
    int t = t0 + tg;
    __shared__ float sc[2][48];
    __shared__ float wl[2][3][16];
    if (threadIdx.x < 96) {
        int tk = threadIdx.x / 48, j = threadIdx.x % 48;
        sc[tk][j] = bu2f(z[(size_t)(t0 + tk)*NZ_ + 2048 + j]);
    }
    __syncthreads();
    if (threadIdx.x < 6) {
        int tk = threadIdx.x / 3, w = threadIdx.x % 3;
        float m = -INFINITY;
        for (int n = 0; n < 16; n++) m = fmaxf(m, sc[tk][w*16 + n]);
        float s = 0.f, e[16];
        for (int n = 0; n < 16; n++) { e[n] = __expf(sc[tk][w*16 + n] - m); s += e[n]; }
        float inv = 1.f / s;
        for (int n = 0; n < 16; n++) wl[tk][w][n] = e[n] * inv;
    }
    __syncthreads();
    const unsigned short* zr = z + (size_t)t * NZ_;
    float acc[3] = {0.f, 0.f, 0.f};
    #pragma unroll
    for (int n = 0; n < NC_; n++) {
        float zv = bu2f(zr[n*RANK_ + r]);
        #pragma unroll
        for (int w = 0; w < 3; w++) acc[w] += wl[tg][w][n] * zv;
    }
    #pragma unroll
    for (int w = 0; w < 3; w++) h[((size_t)w*T_ + t)*RANK_ + r] = f2bu(acc[w]);
}

// ---------------------------------------------------------------------------
// MFMA causal flash attention. PAIRED q-tiles (p, 31-p), 128 keys/iter.
// K double-buffered in LDS (prefetched one full iter ahead); V fragments
// loaded global->registers. ONE barrier per iter. exp2 fixed-max softmax.
// ---------------------------------------------------------------------------
__global__ __launch_bounds__(256) void k_flash_mfma(const unsigned short* __restrict__ Qm,
    const unsigned short* __restrict__ Km, const unsigned short* __restrict__ Vtg,
    unsigned short* __restrict__ Om)
{
    const int p = blockIdx.x, hh = blockIdx.y, b = blockIdx.z;
    __shared__ __align__(16) unsigned short Ks[2][128*64];  // [key][dh], swizzled
    __shared__ __align__(16) unsigned short Ps[64][136];    // [tok][key]
    const int tid = threadIdx.x;
    const int w = tid >> 6, lane = tid & 63;
    const int quad = lane >> 4, l16 = lane & 15;
    const size_t base  = ((size_t)b * S_) * D_ + (size_t)hh * DH_;
    const size_t vbase = (size_t)((b*H_ + hh) * 64) * S_;
    const f32x4 z4 = {0.f, 0.f, 0.f, 0.f};

    for (int rep = 0; rep < 2; rep++) {
        const int qt = rep ? (31 - p) : p;

        bf16x8 aq[2];
        #pragma unroll
        for (int s = 0; s < 2; s++)
            aq[s] = *(const bf16x8*)(Qm + base + (size_t)(qt*64 + w*16 + l16)*D_ + s*32 + quad*8);

        f32x4 oacc[4];
        #pragma unroll
        for (int nt = 0; nt < 4; nt++) oacc[nt] = z4;
        float lsum[4] = {0.f, 0.f, 0.f, 0.f};

        const int nkt = (qt >> 1) + 1;

        __syncthreads();                       // prev rep's LDS reads done
        #pragma unroll
        for (int c = 0; c < 4; c++) {          // prefetch K(0) -> buf 0
            int idx = c*256 + tid;
            int row = idx >> 3, j = (idx & 7) ^ (row & 7);
            gl_lds16(Km + base + (size_t)row*D_ + j*8, &Ks[0][(c*256 + (w<<6))*8]);
        }

        for (int kt = 0; kt < nkt; kt++) {
            const int cur = kt & 1;
            __syncthreads();                   // drains K(kt) DMA (1 iter of flight)

            // V fragments -> registers (oldest vmem this iter)
            bf16x8 vf[4][4];
            #pragma unroll
            for (int s = 0; s < 4; s++)
                #pragma unroll
                for (int nt = 0; nt < 4; nt++)
                    vf[s][nt] = *(const bf16x8*)(Vtg + vbase + (size_t)(nt*16 + l16)*S_
                                                 + kt*128 + s*32 + quad*8);
            // prefetch K(kt+1) -> other buffer (stays in flight through PV)
            if (kt + 1 < nkt) {
                #pragma unroll
                for (int c = 0; c < 4; c++) {
                    int idx = c*256 + tid;
                    int row = idx >> 3, j = (idx & 7) ^ (row & 7);
                    gl_lds16(Km + base + (size_t)((kt+1)*128 + row)*D_ + j*8,
                             &Ks[1-cur][(c*256 + (w<<6))*8]);
                }
            }

            // S = Q K^T (log2 domain): 16 tokens x 128 keys per wave
            f32x4 sacc[8];
            #pragma unroll
            for (int nt = 0; nt < 8; nt++) sacc[nt] = z4;
            #pragma unroll
            for (int s = 0; s < 2; s++)
                #pragma unroll
                for (int nt = 0; nt < 8; nt++) {
                    int row = nt*16 + l16;
                    int cc = (s*4 + quad) ^ (row & 7);
                    bf16x8 bk = *(const bf16x8*)&Ks[cur][row*64 + cc*8];
                    sacc[nt] = __builtin_amdgcn_mfma_f32_16x16x32_bf16(aq[s], bk, sacc[nt], 0, 0, 0);
                }
            if (kt == (qt >> 1)) {             // diagonal tile: causal mask
                #pragma unroll
                for (int nt = 0; nt < 8; nt++) {
                    int key = kt*128 + nt*16 + l16;
                    #pragma unroll
                    for (int r = 0; r < 4; r++)
                        if (key > qt*64 + w*16 + quad*4 + r) sacc[nt][r] = -INFINITY;
                }
            }
            #pragma unroll
            for (int r = 0; r < 4; r++) {
                float rs = 0.f;
                #pragma unroll
                for (int nt = 0; nt < 8; nt++) {
                    float pv = EXP2F(sacc[nt][r]);
                    rs += pv;
                    Ps[w*16 + quad*4 + r][nt*16 + l16] = f2bu(pv);
                }
                lsum[r] += rs;
            }
            // O += P V  (P per-wave strip; V from registers)
            #pragma unroll
            for (int s = 0; s < 4; s++) {
                bf16x8 ap = *(const bf16x8*)&Ps[w*16 + l16][s*32 + quad*8];
                #pragma unroll
                for (int nt = 0; nt < 4; nt++)
                    oacc[nt] = __builtin_amdgcn_mfma_f32_16x16x32_bf16(ap, vf[s][nt], oacc[nt], 0, 0, 0);
            }
        }
        #pragma unroll
        for (int r = 0; r < 4; r++) {
            float l = lsum[r];
            #pragma unroll
            for (int off = 1; off < 16; off <<= 1) l += __shfl_xor(l, off, 64);
            float inv = 1.f / l;
            int tok = qt*64 + w*16 + quad*4 + r;
            #pragma unroll
            for (int nt = 0; nt < 4; nt++)
                Om[base + (size_t)tok*D_ + nt*16 + l16] = f2bu(oacc[nt][r] * inv);
        }
    }
}

// ---------------------------------------------------------------------------
// launch
// ---------------------------------------------------------------------------
extern "C" void kernel_launch(void* const* d_in, const int* in_sizes, int n_in,
                              void* d_out, int out_size, void* d_ws, size_t ws_size,
                              hipStream_t stream)
{
    const unsigned* probe = (const unsigned*)d_in[0];

    unsigned short* u = (unsigned short*)d_ws;
    unsigned short* xc   = u;               size_t o = (size_t)T_*D_;
    unsigned short* wqkv = u + o;           o += (size_t)3*D_*RANK_;
    unsigned short* wOc  = u + o;           o += (size_t)D_*D_;
    unsigned short* Ct   = u + o;           o += (size_t)NZ_*D_;      // 2048 Ct | 64 Rpad | 64 pad
    unsigned short* h3   = u + o;           o += (size_t)3*T_*RANK_;
    unsigned short* QKb  = u + o;           o += (size_t)2*T_*D_;     // Q | K
    unsigned short* Vtg  = u + o;           o += (size_t)T_*D_;
    unsigned short* z    = u + o;           o += (size_t)T_*NZ_;
    unsigned short* attnb= u + o;           o += (size_t)T_*D_;

    unsigned short* Rp = Ct + (size_t)2048*D_;
    unsigned short* Qb = QKb;
    unsigned short* Kb = QKb + (size_t)T_*D_;

    Cvt cv;
    cv.src[0] = d_in[0]; cv.dst[0] = xc;
    cv.src[1] = d_in[3]; cv.dst[1] = Rp;
    cv.src[2] = d_in[4]; cv.dst[2] = Rp + 16384;
    cv.src[3] = d_in[5]; cv.dst[3] = Rp + 32768;
    cv.src[4] = nullptr; cv.dst[4] = Rp + 49152;
    cv.src[5] = d_in[6]; cv.dst[5] = wqkv;
    cv.src[6] = d_in[7]; cv.dst[6] = wqkv + 131072;
    cv.src[7] = d_in[8]; cv.dst[7] = wqkv + 262144;
    cv.src[8] = d_in[9]; cv.dst[8] = wOc;
    cv.C = d_in[2]; cv.Ct = Ct;
    k_inputs<<<512 + 2048, 256, 0, stream>>>(cv, probe);

    k_mfma_gemm<4,0><<<dim3(T_/128, NZ_/128), 256, 0, stream>>>(
        xc, Ct, z, nullptr, T_, NZ_, D_);

    k_hreduce<<<T_/2, 256, 0, stream>>>(z, h3);

    k_qkv2<<<768, 256, 0, stream>>>(h3, wqkv, QKb, Vtg);

    k_flash_mfma<<<dim3(16, H_, B_), 256, 0, stream>>>(Qb, Kb, Vtg, attnb);

    k_mfma_gemm<2,2><<<dim3(T_/64, D_/128), 256, 0, stream>>>(
        attnb, wOc, d_out, probe, T_, D_, D_);
}

// Round 10
// 237.072 us; speedup vs baseline: 1.1342x; 1.1342x over previous
//
#include <hip/hip_runtime.h>
#include <hip/hip_bf16.h>
#include <math.h>

#define B_ 2
#define S_ 2048
#define D_ 1024
#define H_ 16
#define RANK_ 128
#define NC_ 16
#define DH_ 64
#define T_ (B_*S_)
#define NZ_ 2176          // z cols: 2048 z | 64 scores | 64 pad

typedef __attribute__((ext_vector_type(8))) __bf16 bf16x8;
typedef __attribute__((ext_vector_type(8))) unsigned short u16x8;
typedef __attribute__((ext_vector_type(4))) float f32x4;

#if __has_builtin(__builtin_amdgcn_exp2f)
#define EXP2F(x) __builtin_amdgcn_exp2f(x)
#else
#define EXP2F(x) exp2f(x)
#endif

__device__ __forceinline__ unsigned short f2bu(float f) {
    __hip_bfloat16 h = __float2bfloat16(f);
    unsigned short u; __builtin_memcpy(&u, &h, 2); return u;
}
__device__ __forceinline__ float bu2f(unsigned short u) {
    __hip_bfloat16 h; __builtin_memcpy(&h, &u, 2); return __bfloat162float(h);
}

// async global->LDS 16B/lane; LDS dst = wave-uniform base (+ lane*16 implied)
__device__ __forceinline__ void gl_lds16(const unsigned short* g, unsigned short* l) {
    __builtin_amdgcn_global_load_lds(
        (const __attribute__((address_space(1))) void*)g,
        (__attribute__((address_space(3))) void*)l, 16, 0, 0);
}

__device__ __forceinline__ bool sniff_f32(const unsigned* __restrict__ p) {
    int votes = 0;
    #pragma unroll
    for (int i = 0; i < 64; i++) {
        unsigned e = (p[i] >> 23) & 0xFFu;
        votes += (e >= 0x60u && e <= 0x8Fu) ? 1 : 0;
    }
    return votes >= 32;
}

// ---------------------------------------------------------------------------
// merged input stage: blocks 0..511 = convert+transpose C; rest = flat converts
// ---------------------------------------------------------------------------
struct Cvt { const void* src[9]; unsigned short* dst[9]; const void* C; unsigned short* Ct; };

__global__ __launch_bounds__(256) void k_inputs(Cvt cv,
    const unsigned* __restrict__ probe)
{
    bool f32 = sniff_f32(probe);
    if (blockIdx.x < 512) {
        int bid = blockIdx.x;
        int d0 = (bid & 15) * 64, r0 = ((bid >> 4) & 1) * 64, n = bid >> 5;
        __shared__ unsigned short tile[64][65];
        for (int idx = threadIdx.x; idx < 4096; idx += 256) {
            int row = idx >> 6, col = idx & 63;
            size_t si = ((size_t)n*D_ + d0 + row)*RANK_ + r0 + col;
            tile[row][col] = f32 ? f2bu(((const float*)cv.C)[si])
                                 : ((const unsigned short*)cv.C)[si];
        }
        __syncthreads();
        for (int idx = threadIdx.x; idx < 4096; idx += 256) {
            int row = idx >> 6, col = idx & 63;
            cv.Ct[((size_t)(n*RANK_ + r0 + row))*D_ + d0 + col] = tile[col][row];
        }
        return;
    }
    const int offs[9] = {0, 4194304, 4210688, 4227072, 4243456,
                         4259840, 4390912, 4521984, 4653056};
    const int total = 5701632;
    int nconv = gridDim.x - 512;
    int stride = nconv * 256;
    for (int i = (blockIdx.x - 512) * 256 + threadIdx.x; i < total; i += stride) {
        int seg = 0;
        #pragma unroll
        for (int s = 1; s < 9; s++) seg += (i >= offs[s]) ? 1 : 0;
        int local = i - offs[seg];
        const void* sp = cv.src[seg];
        unsigned short v = 0;
        if (sp) v = f32 ? f2bu(((const float*)sp)[local]) : ((const unsigned short*)sp)[local];
        cv.dst[seg][local] = v;
    }
}

// ---------------------------------------------------------------------------
// MFMA NT GEMM, async-staged. Tile (MT*32)x128, BK=32.
// MODE: 0 = bf16 out; 2 = runtime-sniffed out dtype (fp32 vs bf16)
// ---------------------------------------------------------------------------
template<int MT, int MODE>
__global__ __launch_bounds__(256) void k_mfma_gemm(const unsigned short* __restrict__ A,
    const unsigned short* __restrict__ Bm, void* __restrict__ Cout,
    const unsigned* __restrict__ probe, int M, int N, int K)
{
    bool f32out = false;
    if (MODE == 2) f32out = sniff_f32(probe);
    __shared__ __align__(16) unsigned short As[MT*32*32];
    __shared__ __align__(16) unsigned short Bs[128*32];
    const int tid = threadIdx.x;
    const int wv = tid >> 6, lane = tid & 63;
    const int wm = (wv >> 1) * (MT*16), wn = (wv & 1) * 64;
    const int quad = lane >> 4, l16 = lane & 15;
    const int m0 = blockIdx.x * (MT*32), n0 = blockIdx.y * 128;

    const f32x4 z4 = {0.f, 0.f, 0.f, 0.f};
    f32x4 acc[MT][4];
    #pragma unroll
    for (int i = 0; i < MT; i++)
        #pragma unroll
        for (int j = 0; j < 4; j++) acc[i][j] = z4;

    for (int k0 = 0; k0 < K; k0 += 32) {
        __syncthreads();
        #pragma unroll
        for (int c = 0; c < MT/2; c++) {
            int idx = wv*64 + c*256 + lane;
            gl_lds16(A + (size_t)(m0 + (idx >> 2))*K + k0 + (idx & 3)*8,
                     &As[(wv*64 + c*256)*8]);
        }
        #pragma unroll
        for (int c = 0; c < 2; c++) {
            int idx = wv*64 + c*256 + lane;
            gl_lds16(Bm + (size_t)(n0 + (idx >> 2))*K + k0 + (idx & 3)*8,
                     &Bs[(wv*64 + c*256)*8]);
        }
        __syncthreads();
        bf16x8 af[MT], bfr[4];
        #pragma unroll
        for (int mt = 0; mt < MT; mt++) af[mt]  = *(const bf16x8*)&As[(wm + mt*16 + l16)*32 + quad*8];
        #pragma unroll
        for (int nt = 0; nt < 4; nt++) bfr[nt] = *(const bf16x8*)&Bs[(wn + nt*16 + l16)*32 + quad*8];
        #pragma unroll
        for (int mt = 0; mt < MT; mt++)
            #pragma unroll
            for (int nt = 0; nt < 4; nt++)
                acc[mt][nt] = __builtin_amdgcn_mfma_f32_16x16x32_bf16(af[mt], bfr[nt], acc[mt][nt], 0, 0, 0);
    }
    #pragma unroll
    for (int mt = 0; mt < MT; mt++)
        #pragma unroll
        for (int nt = 0; nt < 4; nt++) {
            int col = n0 + wn + nt*16 + l16;
            #pragma unroll
            for (int r = 0; r < 4; r++) {
                int rowg = m0 + wm + mt*16 + quad*4 + r;
                float v = acc[mt][nt][r];
                if (MODE == 2 && f32out) ((float*)Cout)[(size_t)rowg*N + col] = v;
                else  ((unsigned short*)Cout)[(size_t)rowg*N + col] = f2bu(v);
            }
        }
}

// ---------------------------------------------------------------------------
// merged Q|K + V^T GEMMs (K=128), one launch, 768 blocks.
// ---------------------------------------------------------------------------
__global__ __launch_bounds__(256) void k_qkv2(const unsigned short* __restrict__ h3,
    const unsigned short* __restrict__ wqkv, unsigned short* __restrict__ QKb,
    unsigned short* __restrict__ Vtg)
{
    __shared__ __align__(16) unsigned short As[128*32];
    __shared__ __align__(16) unsigned short Bs[128*32];
    const int tid = threadIdx.x;
    const int wv = tid >> 6, lane = tid & 63;
    const int wm = (wv >> 1) * 64, wn = (wv & 1) * 64;
    const int quad = lane >> 4, l16 = lane & 15;

    const bool vt = (blockIdx.x >= 512);
    int m0, n0;
    const unsigned short *A, *Bm;
    float scale = 1.f;
    if (!vt) {
        int id = blockIdx.x;
        m0 = (id & 31) * 128;                 // tokens
        n0 = (id >> 5) * 128;                 // Q|K cols (0..2047)
        int w = n0 >> 10;
        A  = h3 + (size_t)w * T_ * RANK_ + (size_t)m0 * RANK_;
        Bm = wqkv + (size_t)w * D_ * RANK_ + (size_t)(n0 & 1023) * RANK_;
        if (w == 0) scale = 0.125f * 1.44269504f;
    } else {
        int id = blockIdx.x - 512;
        m0 = (id & 7) * 128;                  // dv rows
        n0 = (id >> 3) * 128;                 // tokens
        A  = wqkv + (size_t)2 * D_ * RANK_ + (size_t)m0 * RANK_;
        Bm = h3 + (size_t)2 * T_ * RANK_ + (size_t)n0 * RANK_;
    }

    const f32x4 z4 = {0.f, 0.f, 0.f, 0.f};
    f32x4 acc[4][4];
    #pragma unroll
    for (int i = 0; i < 4; i++)
        #pragma unroll
        for (int j = 0; j < 4; j++) acc[i][j] = z4;

    for (int k0 = 0; k0 < RANK_; k0 += 32) {
        __syncthreads();
        #pragma unroll
        for (int c = 0; c < 2; c++) {
            int idx = wv*64 + c*256 + lane;
            gl_lds16(A  + (size_t)(idx >> 2)*RANK_ + k0 + (idx & 3)*8,
                     &As[(wv*64 + c*256)*8]);
            gl_lds16(Bm + (size_t)(idx >> 2)*RANK_ + k0 + (idx & 3)*8,
                     &Bs[(wv*64 + c*256)*8]);
        }
        __syncthreads();
        bf16x8 af[4], bfr[4];
        #pragma unroll
        for (int mt = 0; mt < 4; mt++) af[mt]  = *(const bf16x8*)&As[(wm + mt*16 + l16)*32 + quad*8];
        #pragma unroll
        for (int nt = 0; nt < 4; nt++) bfr[nt] = *(const bf16x8*)&Bs[(wn + nt*16 + l16)*32 + quad*8];
        #pragma unroll
        for (int mt = 0; mt < 4; mt++)
            #pragma unroll
            for (int nt = 0; nt < 4; nt++)
                acc[mt][nt] = __builtin_amdgcn_mfma_f32_16x16x32_bf16(af[mt], bfr[nt], acc[mt][nt], 0, 0, 0);
    }
    #pragma unroll
    for (int mt = 0; mt < 4; mt++)
        #pragma unroll
        for (int nt = 0; nt < 4; nt++) {
            #pragma unroll
            for (int r = 0; r < 4; r++) {
                int rowg = m0 + wm + mt*16 + quad*4 + r;
                int col  = n0 + wn + nt*16 + l16;
                float v = acc[mt][nt][r] * scale;
                if (!vt) {
                    QKb[(size_t)(col >> 10)*T_*D_ + (size_t)rowg*D_ + (col & 1023)]
                        = f2bu(v);
                } else {
                    size_t vrow = (size_t)((col >> 11)*H_ + (rowg >> 6))*64 + (rowg & 63);
                    Vtg[vrow*S_ + (col & 2047)] = f2bu(v);
                }
            }
        }
}

// ---------------------------------------------------------------------------
// hreduce + router softmax (scores in z cols 2048..2095)
// ---------------------------------------------------------------------------
__global__ __launch_bounds__(256) void k_hreduce(const unsigned short* __restrict__ z,
    unsigned short* __restrict__ h)
{
    int t0 = blockIdx.x * 2;
    int tg = threadIdx.x >> 7, r = threadIdx.x & 127;
    int t = t0 + tg;
    __shared__ float sc[2][48];
    __shared__ float wl[2][3][16];
    if (threadIdx.x < 96) {
        int tk = threadIdx.x / 48, j = threadIdx.x % 48;
        sc[tk][j] = bu2f(z[(size_t)(t0 + tk)*NZ_ + 2048 + j]);
    }
    __syncthreads();
    if (threadIdx.x < 6) {
        int tk = threadIdx.x / 3, w = threadIdx.x % 3;
        float m = -INFINITY;
        for (int n = 0; n < 16; n++) m = fmaxf(m, sc[tk][w*16 + n]);
        float s = 0.f, e[16];
        for (int n = 0; n < 16; n++) { e[n] = __expf(sc[tk][w*16 + n] - m); s += e[n]; }
        float inv = 1.f / s;
        for (int n = 0; n < 16; n++) wl[tk][w][n] = e[n] * inv;
    }
    __syncthreads();
    const unsigned short* zr = z + (size_t)t * NZ_;
    float acc[3] = {0.f, 0.f, 0.f};
    #pragma unroll
    for (int n = 0; n < NC_; n++) {
        float zv = bu2f(zr[n*RANK_ + r]);
        #pragma unroll
        for (int w = 0; w < 3; w++) acc[w] += wl[tg][w][n] * zv;
    }
    #pragma unroll
    for (int w = 0; w < 3; w++) h[((size_t)w*T_ + t)*RANK_ + r] = f2bu(acc[w]);
}

// ---------------------------------------------------------------------------
// MFMA causal flash attention. PAIRED q-tiles (p, 31-p), 128 keys/iter.
// BOTH K and V double-buffered in LDS via async DMA, prefetched one full
// iteration ahead -> ONE barrier/iter whose vmcnt(0) drain waits on loads
// with a whole iteration of flight time. Ps XOR-swizzled (16 KB) so total
// LDS = 32+32+16 KB = 81920 B exactly -> 2 blocks/CU (2x81920 = 160 KiB).
// exp2 fixed-max softmax (scores bounded; Q pre-scaled by 0.125*log2e).
// ---------------------------------------------------------------------------
__global__ __launch_bounds__(256) void k_flash_mfma(const unsigned short* __restrict__ Qm,
    const unsigned short* __restrict__ Km, const unsigned short* __restrict__ Vtg,
    unsigned short* __restrict__ Om)
{
    const int p = blockIdx.x, hh = blockIdx.y, b = blockIdx.z;
    __shared__ __align__(16) unsigned short Ks[2][128*64];  // [key][dh], xor-swizzled
    __shared__ __align__(16) unsigned short Vs[2][64*128];  // [dh][key], xor-swizzled
    __shared__ __align__(16) unsigned short Ps[64*128];     // [tok][key], xor-swizzled
    const int tid = threadIdx.x;
    const int w = tid >> 6, lane = tid & 63;
    const int quad = lane >> 4, l16 = lane & 15;
    const size_t base  = ((size_t)b * S_) * D_ + (size_t)hh * DH_;
    const size_t vbase = (size_t)((b*H_ + hh) * 64) * S_;
    const f32x4 z4 = {0.f, 0.f, 0.f, 0.f};

    for (int rep = 0; rep < 2; rep++) {
        const int qt = rep ? (31 - p) : p;

        bf16x8 aq[2];
        #pragma unroll
        for (int s = 0; s < 2; s++)
            aq[s] = *(const bf16x8*)(Qm + base + (size_t)(qt*64 + w*16 + l16)*D_ + s*32 + quad*8);

        f32x4 oacc[4];
        #pragma unroll
        for (int nt = 0; nt < 4; nt++) oacc[nt] = z4;
        float lsum[4] = {0.f, 0.f, 0.f, 0.f};

        const int nkt = (qt >> 1) + 1;

        __syncthreads();                       // prev rep's LDS reads complete
        #pragma unroll
        for (int c = 0; c < 4; c++) {          // prefetch K(0) -> buf 0
            int idx = c*256 + tid;
            int row = idx >> 3, j = (idx & 7) ^ (row & 7);
            gl_lds16(Km + base + (size_t)row*D_ + j*8, &Ks[0][(c*256 + (w<<6))*8]);
        }
        #pragma unroll
        for (int c = 0; c < 4; c++) {          // prefetch V(0) -> buf 0
            int idx = c*256 + tid;
            int row = idx >> 4, j = (idx & 15) ^ (row & 7);
            gl_lds16(Vtg + vbase + (size_t)row*S_ + j*8, &Vs[0][(c*256 + (w<<6))*8]);
        }

        for (int kt = 0; kt < nkt; kt++) {
            const int cur = kt & 1;
            __syncthreads();                   // drains tile-kt DMA (full-iter flight)

            if (kt + 1 < nkt) {                // prefetch tile kt+1 -> other buffers
                #pragma unroll
                for (int c = 0; c < 4; c++) {
                    int idx = c*256 + tid;
                    int row = idx >> 3, j = (idx & 7) ^ (row & 7);
                    gl_lds16(Km + base + (size_t)((kt+1)*128 + row)*D_ + j*8,
                             &Ks[1-cur][(c*256 + (w<<6))*8]);
                }
                #pragma unroll
                for (int c = 0; c < 4; c++) {
                    int idx = c*256 + tid;
                    int row = idx >> 4, j = (idx & 15) ^ (row & 7);
                    gl_lds16(Vtg + vbase + (size_t)row*S_ + (kt+1)*128 + j*8,
                             &Vs[1-cur][(c*256 + (w<<6))*8]);
                }
            }

            // S = Q K^T (log2 domain): 16 tokens x 128 keys per wave
            f32x4 sacc[8];
            #pragma unroll
            for (int nt = 0; nt < 8; nt++) sacc[nt] = z4;
            #pragma unroll
            for (int s = 0; s < 2; s++)
                #pragma unroll
                for (int nt = 0; nt < 8; nt++) {
                    int row = nt*16 + l16;
                    int cc = (s*4 + quad) ^ (row & 7);
                    bf16x8 bk = *(const bf16x8*)&Ks[cur][row*64 + cc*8];
                    sacc[nt] = __builtin_amdgcn_mfma_f32_16x16x32_bf16(aq[s], bk, sacc[nt], 0, 0, 0);
                }
            if (kt == (qt >> 1)) {             // diagonal tile: causal mask
                #pragma unroll
                for (int nt = 0; nt < 8; nt++) {
                    int key = kt*128 + nt*16 + l16;
                    #pragma unroll
                    for (int r = 0; r < 4; r++)
                        if (key > qt*64 + w*16 + quad*4 + r) sacc[nt][r] = -INFINITY;
                }
            }
            // p = exp2(s'); P -> LDS per-wave strip (xor-swizzled chunks)
            #pragma unroll
            for (int r = 0; r < 4; r++) {
                float rs = 0.f;
                int tokl = quad*4 + r;                 // tok & 7 == tokl & 7
                #pragma unroll
                for (int nt = 0; nt < 8; nt++) {
                    float pv = EXP2F(sacc[nt][r]);
                    rs += pv;
                    int pc = (nt*2 + (l16 >> 3)) ^ (tokl & 7);
                    Ps[(w*16 + tokl)*128 + pc*8 + (l16 & 7)] = f2bu(pv);
                }
                lsum[r] += rs;
            }
            // O += P V  (Ps strip per-wave; same-wave RAW via lgkmcnt)
            #pragma unroll
            for (int s = 0; s < 4; s++) {
                int pc = (s*4 + quad) ^ (l16 & 7);
                bf16x8 ap = *(const bf16x8*)&Ps[(w*16 + l16)*128 + pc*8];
                #pragma unroll
                for (int nt = 0; nt < 4; nt++) {
                    int row = nt*16 + l16;
                    int cc = (s*4 + quad) ^ (row & 7);
                    bf16x8 bv = *(const bf16x8*)&Vs[cur][row*128 + cc*8];
                    oacc[nt] = __builtin_amdgcn_mfma_f32_16x16x32_bf16(ap, bv, oacc[nt], 0, 0, 0);
                }
            }
        }
        #pragma unroll
        for (int r = 0; r < 4; r++) {
            float l = lsum[r];
            #pragma unroll
            for (int off = 1; off < 16; off <<= 1) l += __shfl_xor(l, off, 64);
            float inv = 1.f / l;
            int tok = qt*64 + w*16 + quad*4 + r;
            #pragma unroll
            for (int nt = 0; nt < 4; nt++)
                Om[base + (size_t)tok*D_ + nt*16 + l16] = f2bu(oacc[nt][r] * inv);
        }
    }
}

// ---------------------------------------------------------------------------
// launch
// ---------------------------------------------------------------------------
extern "C" void kernel_launch(void* const* d_in, const int* in_sizes, int n_in,
                              void* d_out, int out_size, void* d_ws, size_t ws_size,
                              hipStream_t stream)
{
    const unsigned* probe = (const unsigned*)d_in[0];

    unsigned short* u = (unsigned short*)d_ws;
    unsigned short* xc   = u;               size_t o = (size_t)T_*D_;
    unsigned short* wqkv = u + o;           o += (size_t)3*D_*RANK_;
    unsigned short* wOc  = u + o;           o += (size_t)D_*D_;
    unsigned short* Ct   = u + o;           o += (size_t)NZ_*D_;      // 2048 Ct | 64 Rpad | 64 pad
    unsigned short* h3   = u + o;           o += (size_t)3*T_*RANK_;
    unsigned short* QKb  = u + o;           o += (size_t)2*T_*D_;     // Q | K
    unsigned short* Vtg  = u + o;           o += (size_t)T_*D_;
    unsigned short* z    = u + o;           o += (size_t)T_*NZ_;
    unsigned short* attnb= u + o;           o += (size_t)T_*D_;

    unsigned short* Rp = Ct + (size_t)2048*D_;
    unsigned short* Qb = QKb;
    unsigned short* Kb = QKb + (size_t)T_*D_;

    Cvt cv;
    cv.src[0] = d_in[0]; cv.dst[0] = xc;
    cv.src[1] = d_in[3]; cv.dst[1] = Rp;
    cv.src[2] = d_in[4]; cv.dst[2] = Rp + 16384;
    cv.src[3] = d_in[5]; cv.dst[3] = Rp + 32768;
    cv.src[4] = nullptr; cv.dst[4] = Rp + 49152;
    cv.src[5] = d_in[6]; cv.dst[5] = wqkv;
    cv.src[6] = d_in[7]; cv.dst[6] = wqkv + 131072;
    cv.src[7] = d_in[8]; cv.dst[7] = wqkv + 262144;
    cv.src[8] = d_in[9]; cv.dst[8] = wOc;
    cv.C = d_in[2]; cv.Ct = Ct;
    k_inputs<<<512 + 2048, 256, 0, stream>>>(cv, probe);

    k_mfma_gemm<4,0><<<dim3(T_/128, NZ_/128), 256, 0, stream>>>(
        xc, Ct, z, nullptr, T_, NZ_, D_);

    k_hreduce<<<T_/2, 256, 0, stream>>>(z, h3);

    k_qkv2<<<768, 256, 0, stream>>>(h3, wqkv, QKb, Vtg);

    k_flash_mfma<<<dim3(16, H_, B_), 256, 0, stream>>>(Qb, Kb, Vtg, attnb);

    k_mfma_gemm<2,2><<<dim3(T_/64, D_/128), 256, 0, stream>>>(
        attnb, wOc, d_out, probe, T_, D_, D_);
}